// Round 12
// baseline (196.976 us; speedup 1.0000x reference)
//
#include <hip/hip_runtime.h>
#include <hip/hip_fp16.h>

#define T1 512
#define NB 32      // batches
#define NP 96      // 3 pairs * 32 batches
#define DHEAD 64

#define RSLOTS 128                 // W-ring slots per wave (512B column slice each)
#define WRING  65536               // 64 KB ring per wave
#define PFD 24                     // producer prefetch distance (columns ahead)
#define NIDLE 9                    // idle groups = 72-step wave-1 shift

typedef __attribute__((ext_vector_type(8))) short bf16x8;
typedef __attribute__((ext_vector_type(4))) float f32x4;

// ---------------- kernel 1: row-normalize x,y -> bf16 ----------------
__global__ __launch_bounds__(256) void k_normalize(const float* __restrict__ x,
                                                   const float* __restrict__ y,
                                                   ushort* __restrict__ xb,
                                                   ushort* __restrict__ yb) {
  int wid  = threadIdx.x >> 6;
  int lane = threadIdx.x & 63;
  int row  = blockIdx.x * 4 + wid;          // 0 .. 32767
  const float* src; ushort* dst;
  if (row < NB * T1) { src = x + (size_t)row * DHEAD;            dst = xb + (size_t)row * DHEAD; }
  else { int r2 = row - NB * T1; src = y + (size_t)r2 * DHEAD;   dst = yb + (size_t)r2 * DHEAD; }
  float v = src[lane];
  float s = v * v;
  #pragma unroll
  for (int off = 32; off > 0; off >>= 1) s += __shfl_xor(s, off);
  float rn = 1.0f / fmaxf(sqrtf(s), 1e-12f);
  float o = v * rn;
  unsigned u = __float_as_uint(o);
  unsigned r = (u + 0x7fffu + ((u >> 16) & 1u)) >> 16;   // RNE to bf16
  dst[lane] = (ushort)r;
}

// ---------------- kernel 2: MFMA bf16 GEMM -> W[p][b][j][i] = exp(-(1-dot)) f16 ----------------
__global__ __launch_bounds__(256) void k_gemm_w(const ushort* __restrict__ xb,
                                                const ushort* __restrict__ yb,
                                                __half* __restrict__ W) {
  int pb = blockIdx.z;            // 0..95
  int p  = pb >> 5;               // 0:xy 1:xx 2:yy
  int b  = pb & 31;
  const ushort* A  = ((p == 2) ? yb : xb) + (size_t)b * T1 * DHEAD;  // i-side (M)
  const ushort* Bm = ((p == 1) ? xb : yb) + (size_t)b * T1 * DHEAD;  // j-side (N)

  int wid = threadIdx.x >> 6, lane = threadIdx.x & 63;
  int wm = wid >> 1, wn = wid & 1;
  int i0 = blockIdx.x * 128 + wm * 64;
  int j0 = blockIdx.y * 128 + wn * 64;
  int lr = lane & 15, kg = lane >> 4;

  f32x4 acc[4][4];
  #pragma unroll
  for (int ic = 0; ic < 4; ++ic)
    #pragma unroll
    for (int jc = 0; jc < 4; ++jc) acc[ic][jc] = (f32x4){0.f, 0.f, 0.f, 0.f};

  #pragma unroll
  for (int kk = 0; kk < 2; ++kk) {
    int ko = kk * 32 + kg * 8;
    bf16x8 af[4], bf[4];
    #pragma unroll
    for (int ic = 0; ic < 4; ++ic)
      af[ic] = *reinterpret_cast<const bf16x8*>(A + (size_t)(i0 + ic * 16 + lr) * DHEAD + ko);
    #pragma unroll
    for (int jc = 0; jc < 4; ++jc)
      bf[jc] = *reinterpret_cast<const bf16x8*>(Bm + (size_t)(j0 + jc * 16 + lr) * DHEAD + ko);
    #pragma unroll
    for (int ic = 0; ic < 4; ++ic)
      #pragma unroll
      for (int jc = 0; jc < 4; ++jc)
        acc[ic][jc] = __builtin_amdgcn_mfma_f32_16x16x32_bf16(af[ic], bf[jc], acc[ic][jc], 0, 0, 0);
  }

  const float NLOG2E = -1.44269504088896340736f;
  __half* Wp = W + (size_t)pb * (T1 * T1);
  int ib = kg << 2;
  #pragma unroll
  for (int ic = 0; ic < 4; ++ic) {
    int i = i0 + ic * 16 + ib;
    #pragma unroll
    for (int jc = 0; jc < 4; ++jc) {
      int j = j0 + jc * 16 + lr;
      union { __half h[4]; uint2 u; } pk;
      #pragma unroll
      for (int r = 0; r < 4; ++r) {
        float d = 1.0f - acc[ic][jc][r];
        pk.h[r] = __float2half(exp2f(NLOG2E * d));
      }
      *reinterpret_cast<uint2*>(Wp + (size_t)j * T1 + i) = pk.u;
    }
  }
}

// ---------------- kernel 3: soft-DTW, exp domain, 2 waves x 4 rows/lane, shifted clock ----
// Wave 0: DP rows 1..256 on local time t (groups tb=0..568, then 9 idle barriers).
// Wave 1: DP rows 257..512 on local time t1 = t-72 (9 idle barriers, then tb=0..568).
// Both waves run IDENTICAL round-10-style machinery on their local clock: lane l works
// col j = tb+KK - l; ring slot (col)&127; producer issues col t+24 (2x GLL4 of the
// wave's own 512B column slice); one counted vmcnt(16) per group. Handoff: wave0 lane63
// writes its row-256 value (pre-renorm, 1-step delayed) to hval[col&127], per-group base
// to hbase[g&31]; published by lgkmcnt(0)+s_barrier. Consumer group g1 (joint barrier
// 10+g1) reads cols 8g1..8g1+7 — written during wave0 group g1+8, complete by joint
// barrier g1+10 <= 10+g1 (exact). Bases: hv[0] is writer's KK7 pre-renorm capture ->
// hbase[g1+7]; hv[1..7] -> hbase[g1+8]; wg = tb/8+8. Barrier counts 81 = 81.
// Margins (per wave, round-10 proven): slot c rewritten at issue of col c+128 at local
// step c+104 > last ds_read of col c at local step c+55. vmcnt(16) -> cols <= tb+15
// landed at group top (need d7 col tb+7, refills <= tb+15). Tail garbage contained:
// corruption reaches lane l at local step 512+l > its last active 511+l; final group
// guarded for lanes 57..63; all values provably finite (W<=1, scales clamped 2^±120).
__global__ __launch_bounds__(128, 1) void k_dtw(const __half* __restrict__ W,
                                                float* __restrict__ res) {
  __shared__ __attribute__((aligned(16))) char ring[2 * WRING];
  __shared__ __attribute__((aligned(16))) float hval[RSLOTS];
  __shared__ float hbase[32];
  const int prob = blockIdx.x;
  const __half* Wp = W + (size_t)prob * (T1 * T1);
  const int tid  = threadIdx.x;
  const int lane = tid & 63;
  const int w    = __builtin_amdgcn_readfirstlane(tid >> 6);   // 0 or 1, wave-uniform

  const char* gbase = (const char*)Wp + (w << 9);   // wave's 512B slice base in column
  char* ringw = ring + (w << 16);

  float Va[4], Vb[4];
  #pragma unroll
  for (int r = 0; r < 4; ++r) { Va[r] = 0.f; Vb[r] = 0.f; }
  float B2 = 0.f, B2p = 0.f;       // per-lane base (log2 units, int-valued, exact)
  float cSave = 0.f;               // wave0 lane63: delayed handoff value (pre-renorm)
  float dgl0  = 0.f;               // wave1 lane0: saved diag (prev step's up)
  unsigned hw = 256;               // hval write byte offset for local step 0 (col -64)

  auto dppshr = [](float v) -> float {   // lane l <- lane l-1; lane 0 <- 0 (VALU only)
    return __int_as_float(__builtin_amdgcn_update_dpp(
        0, __float_as_int(v), 0x138 /*wave_shr:1*/, 0xF, 0xF, true));
  };

#define SCALEBITS(dexp) __uint_as_float( \
    (unsigned)(127 + (int)fminf(fmaxf((dexp), -120.f), 120.f)) << 23)

#define GLL4(GP, LP) __builtin_amdgcn_global_load_lds( \
    (const __attribute__((address_space(1))) void*)(GP), \
    (__attribute__((address_space(3))) void*)(LP), 4, 0, 0)

  // -------- producer prologue: issue cols 0..PFD-1 (2 loads each) --------
  #pragma unroll
  for (int c = 0; c < PFD; ++c) {
    const char* gp = gbase + ((size_t)c << 10);
    char* lp = ringw + ((unsigned)c << 9);
    GLL4(gp + (lane << 2), lp);
    GLL4(gp + 256 + (lane << 2), lp + 256);
  }
  asm volatile("s_waitcnt vmcnt(32)" ::: "memory");   // cols 0..7 landed

  // consumer buffers for local steps 0..7 (lane-skewed slots!), persistent refill addrs
  uint2 d0, d1, d2, d3, d4, d5, d6, d7;
  unsigned va0, va1, va2, va3, va4, va5, va6, va7;
#define RS_INIT(K) do { \
    d##K = *reinterpret_cast<const uint2*>( \
        ringw + ((((unsigned)((K) - lane) & 127u) << 9) | (unsigned)(lane << 3))); \
    va##K = ((((unsigned)((K) + 8 - lane) & 127u) << 9) | (unsigned)(lane << 3)); \
  } while (0)
  RS_INIT(0); RS_INIT(1); RS_INIT(2); RS_INIT(3); RS_INIT(4); RS_INIT(5); RS_INIT(6);
#undef RS_INIT
  va7 = ((((unsigned)(7 - lane) & 127u) << 9) | (unsigned)(lane << 3));  // d7 at group top

#define DTW_STEP2(KK, VIN, VOUT, SDG, SEEDK, GUARD, ISW0) do {                \
    const int t_ = tb + (KK);                                                 \
    if (ISW0) {                      /* delayed handoff write at step top */  \
      if (lane == 63) {                                                       \
        *reinterpret_cast<float*>(reinterpret_cast<char*>(hval) + hw) = cSave;\
        if ((KK) == 0) hbase[(tb >> 3) & 31] = B2;                            \
      }                                                                       \
      hw = (hw + 4u) & 511u;                                                  \
    }                                                                         \
    float nbUp_ = dppshr(VIN[3]);            /* neighbor end of t-1 */        \
    float nbDg_ = dppshr(VOUT[3]);           /* neighbor end of t-2 */        \
    float up_ = nbUp_ * sUp;                                                  \
    float dg_ = nbDg_ * (SDG);                                                \
    if (!ISW0) {                             /* wave1 lane0: handoff path */  \
      float hup_ = hv[KK] * ((KK) == 0 ? sH0 : sH1);                          \
      up_ = (lane == 0) ? hup_ : up_;                                         \
      dg_ = (lane == 0) ? dgl0 : dg_;                                         \
      dgl0 = hup_;                                                            \
    }                                                                         \
    if (SEEDK) dg_ = (lane == 0) ? 1.0f : dg_;      /* E[0][0]=1 at t=0 */    \
    union { uint2 u; __half h[4]; } cv_; cv_.u = d##KK;                       \
    if ((KK) != 7) {                          /* refill: col t_+8-lane */     \
      d##KK = *reinterpret_cast<const uint2*>(ringw + va##KK);                \
      va##KK = (va##KK + 4096u) & (WRING - 1);                                \
    }                                                                         \
    { int cc_ = t_ + PFD; cc_ = cc_ > T1 - 1 ? T1 - 1 : cc_;                  \
      const char* gp_ = gbase + ((size_t)cc_ << 10);                          \
      char* lp_ = ringw + (((unsigned)cc_ & 127u) << 9);                      \
      GLL4(gp_ + (lane << 2), lp_);                                           \
      GLL4(gp_ + 256 + (lane << 2), lp_ + 256);                               \
    }                                                                         \
    float w0_ = __half2float(cv_.h[0]), w1_ = __half2float(cv_.h[1]);         \
    float w2_ = __half2float(cv_.h[2]), w3_ = __half2float(cv_.h[3]);         \
    bool act_ = true;                                                         \
    if (GUARD) { int j_ = t_ - lane; act_ = ((unsigned)j_ < (unsigned)T1); }  \
    if (act_) {                                                               \
      float c_ = fmaf(w0_, up_, w0_ * (dg_ + VIN[0]));  VOUT[0] = c_;         \
      c_ = fmaf(w1_, c_, w1_ * (VIN[0] + VIN[1]));      VOUT[1] = c_;         \
      c_ = fmaf(w2_, c_, w2_ * (VIN[1] + VIN[2]));      VOUT[2] = c_;         \
      c_ = fmaf(w3_, c_, w3_ * (VIN[2] + VIN[3]));      VOUT[3] = c_;         \
      if (ISW0) cSave = c_;                  /* pre-renorm handoff value */   \
      if ((KK) == 7) {                       /* exact pow2 renorm */          \
        float m_ = fmaxf(fmaxf(VOUT[0], VOUT[1]), fmaxf(VOUT[2], VOUT[3]));   \
        int e_ = (int)((__float_as_uint(m_) >> 23) & 0xFF) - 127;             \
        e_ = e_ < -126 ? -126 : (e_ > 126 ? 126 : e_);                        \
        float sc_ = __uint_as_float((unsigned)(127 - e_) << 23);              \
        VOUT[0] *= sc_; VOUT[1] *= sc_; VOUT[2] *= sc_; VOUT[3] *= sc_;       \
        if (!ISW0) dgl0 *= sc_;                                               \
        B2p = B2; B2 -= (float)e_;                                            \
      }                                                                       \
    }                                                                         \
  } while (0)

#define DTW_GROUP2(GUARD, SEED, ISW0) do {                                    \
    if (ISW0) { asm volatile("s_waitcnt lgkmcnt(0)" ::: "memory"); }          \
    __builtin_amdgcn_s_barrier();                                             \
    asm volatile("" ::: "memory");                                            \
    asm volatile("s_waitcnt vmcnt(16)" ::: "memory");  /* cols <= tb+15 */    \
    d7 = *reinterpret_cast<const uint2*>(ringw + va7); /* col tb+7-lane */    \
    va7 = (va7 + 4096u) & (WRING - 1);                                        \
    float nbBn_ = dppshr(B2);                                                 \
    float nbBo_ = dppshr(B2p);                                                \
    float sUp  = SCALEBITS(B2 - nbBn_);                                       \
    float sDg0 = SCALEBITS(B2 - nbBo_);                                       \
    float hv[8] = {0.f,0.f,0.f,0.f,0.f,0.f,0.f,0.f};                          \
    float sH0 = 0.f, sH1 = 0.f;                                               \
    if (!ISW0) {                                                              \
      int c0_ = tb & 127;                        /* cols tb..tb+7 */          \
      f32x4 ha_ = *reinterpret_cast<const f32x4*>(hval + c0_);                \
      f32x4 hb_ = *reinterpret_cast<const f32x4*>(hval + c0_ + 4);            \
      hv[0]=ha_[0]; hv[1]=ha_[1]; hv[2]=ha_[2]; hv[3]=ha_[3];                 \
      hv[4]=hb_[0]; hv[5]=hb_[1]; hv[6]=hb_[2]; hv[7]=hb_[3];                 \
      int wg_ = (tb >> 3) + 8;                                                \
      sH1 = SCALEBITS(B2 - hbase[wg_ & 31]);        /* hv[1..7] base */       \
      sH0 = SCALEBITS(B2 - hbase[(wg_ - 1) & 31]);  /* hv[0]: KK7 pre-renorm */\
    }                                                                         \
    DTW_STEP2(0, Va, Vb, sDg0, SEED,  GUARD, ISW0);                           \
    DTW_STEP2(1, Vb, Va, sUp,  false, GUARD, ISW0);                           \
    DTW_STEP2(2, Va, Vb, sUp,  false, GUARD, ISW0);                           \
    DTW_STEP2(3, Vb, Va, sUp,  false, GUARD, ISW0);                           \
    DTW_STEP2(4, Va, Vb, sUp,  false, GUARD, ISW0);                           \
    DTW_STEP2(5, Vb, Va, sUp,  false, GUARD, ISW0);                           \
    DTW_STEP2(6, Va, Vb, sUp,  false, GUARD, ISW0);                           \
    DTW_STEP2(7, Vb, Va, sUp,  false, GUARD, ISW0);                           \
  } while (0)

  // 72 real groups per wave + NIDLE idle barriers; joint barrier count 81 = 81.
  if (w == 0) {
    { const int tb = 0; DTW_GROUP2(true, true, 1); }
    #pragma unroll 1
    for (int tb = 8; tb < 64; tb += 8)   DTW_GROUP2(true,  false, 1);
    #pragma unroll 1
    for (int tb = 64; tb < 568; tb += 8) DTW_GROUP2(false, false, 1);
    { const int tb = 568; DTW_GROUP2(true, false, 1); }
    #pragma unroll 1
    for (int i = 0; i < NIDLE; ++i) {    // publish last group's hval, then idle
      asm volatile("s_waitcnt lgkmcnt(0)" ::: "memory");
      __builtin_amdgcn_s_barrier();
      asm volatile("" ::: "memory");
    }
  } else {
    #pragma unroll 1
    for (int i = 0; i < NIDLE; ++i) {
      __builtin_amdgcn_s_barrier();
      asm volatile("" ::: "memory");
    }
    #pragma unroll 1
    for (int tb = 0; tb < 64; tb += 8)   DTW_GROUP2(true,  false, 0);
    #pragma unroll 1
    for (int tb = 64; tb < 568; tb += 8) DTW_GROUP2(false, false, 0);
    { const int tb = 568; DTW_GROUP2(true, false, 0); }
  }

  if (w == 1 && lane == 63) {
    // lane63 last active local step 574 (KK6 of tb=568) wrote Vb; R[512][512]:
    res[prob] = (B2 - log2f(Vb[3])) * 0.69314718055994530942f;
  }
#undef DTW_STEP2
#undef DTW_GROUP2
#undef SCALEBITS
#undef GLL4
}

// ---------------- kernel 4: combine ----------------
__global__ void k_combine(const float* __restrict__ res, float* __restrict__ out) {
  int b = threadIdx.x;
  if (b < NB) out[b] = res[b] - 0.5f * (res[NB + b] + res[2 * NB + b]);
}

extern "C" void kernel_launch(void* const* d_in, const int* in_sizes, int n_in,
                              void* d_out, int out_size, void* d_ws, size_t ws_size,
                              hipStream_t stream) {
  const float* x = (const float*)d_in[0];
  const float* y = (const float*)d_in[1];
  float* out = (float*)d_out;

  const size_t xb_off  = 0;
  const size_t yb_off  = (size_t)NB * T1 * DHEAD * sizeof(ushort);           // 2 MB
  const size_t W_off   = 2 * yb_off;                                          // 4 MB
  const size_t res_off = W_off + (size_t)3 * NB * T1 * T1 * sizeof(__half);   // +50.33 MB
  const size_t need    = res_off + NP * sizeof(float);

  if (ws_size < need) {
    hipMemsetAsync(d_out, 0xFF, (size_t)out_size * sizeof(float), stream);
    return;
  }

  ushort* xb  = (ushort*)((char*)d_ws + xb_off);
  ushort* yb  = (ushort*)((char*)d_ws + yb_off);
  __half* W   = (__half*)((char*)d_ws + W_off);
  float*  res = (float*)((char*)d_ws + res_off);

  hipLaunchKernelGGL(k_normalize, dim3(8192), dim3(256), 0, stream, x, y, xb, yb);
  hipLaunchKernelGGL(k_gemm_w, dim3(4, 4, 96), dim3(256), 0, stream, xb, yb, W);
  hipLaunchKernelGGL(k_dtw, dim3(NP), dim3(128), 0, stream, W, res);
  hipLaunchKernelGGL(k_combine, dim3(1), dim3(64), 0, stream, res, out);
}

// Round 13
// 196.478 us; speedup vs baseline: 1.0025x; 1.0025x over previous
//
#include <hip/hip_runtime.h>
#include <hip/hip_fp16.h>

#define T1 512
#define NB 32      // batches
#define NP 96      // 3 pairs * 32 batches
#define DHEAD 64

#define RSLOTS 128                 // W-ring slots per wave (512B column slice each)
#define WRING  65536               // 64 KB ring per wave
#define PFD 32                     // producer prefetch distance (columns ahead)
#define NIDLE 9                    // idle groups = 72-step wave-1 shift

typedef __attribute__((ext_vector_type(8))) short bf16x8;
typedef __attribute__((ext_vector_type(4))) float f32x4;

// ---------------- kernel 1: row-normalize x,y -> bf16 ----------------
__global__ __launch_bounds__(256) void k_normalize(const float* __restrict__ x,
                                                   const float* __restrict__ y,
                                                   ushort* __restrict__ xb,
                                                   ushort* __restrict__ yb) {
  int wid  = threadIdx.x >> 6;
  int lane = threadIdx.x & 63;
  int row  = blockIdx.x * 4 + wid;          // 0 .. 32767
  const float* src; ushort* dst;
  if (row < NB * T1) { src = x + (size_t)row * DHEAD;            dst = xb + (size_t)row * DHEAD; }
  else { int r2 = row - NB * T1; src = y + (size_t)r2 * DHEAD;   dst = yb + (size_t)r2 * DHEAD; }
  float v = src[lane];
  float s = v * v;
  #pragma unroll
  for (int off = 32; off > 0; off >>= 1) s += __shfl_xor(s, off);
  float rn = 1.0f / fmaxf(sqrtf(s), 1e-12f);
  float o = v * rn;
  unsigned u = __float_as_uint(o);
  unsigned r = (u + 0x7fffu + ((u >> 16) & 1u)) >> 16;   // RNE to bf16
  dst[lane] = (ushort)r;
}

// ---------------- kernel 2: MFMA bf16 GEMM -> W[p][b][j][i] = exp(-(1-dot)) f16 ----------------
__global__ __launch_bounds__(256) void k_gemm_w(const ushort* __restrict__ xb,
                                                const ushort* __restrict__ yb,
                                                __half* __restrict__ W) {
  int pb = blockIdx.z;            // 0..95
  int p  = pb >> 5;               // 0:xy 1:xx 2:yy
  int b  = pb & 31;
  const ushort* A  = ((p == 2) ? yb : xb) + (size_t)b * T1 * DHEAD;  // i-side (M)
  const ushort* Bm = ((p == 1) ? xb : yb) + (size_t)b * T1 * DHEAD;  // j-side (N)

  int wid = threadIdx.x >> 6, lane = threadIdx.x & 63;
  int wm = wid >> 1, wn = wid & 1;
  int i0 = blockIdx.x * 128 + wm * 64;
  int j0 = blockIdx.y * 128 + wn * 64;
  int lr = lane & 15, kg = lane >> 4;

  f32x4 acc[4][4];
  #pragma unroll
  for (int ic = 0; ic < 4; ++ic)
    #pragma unroll
    for (int jc = 0; jc < 4; ++jc) acc[ic][jc] = (f32x4){0.f, 0.f, 0.f, 0.f};

  #pragma unroll
  for (int kk = 0; kk < 2; ++kk) {
    int ko = kk * 32 + kg * 8;
    bf16x8 af[4], bf[4];
    #pragma unroll
    for (int ic = 0; ic < 4; ++ic)
      af[ic] = *reinterpret_cast<const bf16x8*>(A + (size_t)(i0 + ic * 16 + lr) * DHEAD + ko);
    #pragma unroll
    for (int jc = 0; jc < 4; ++jc)
      bf[jc] = *reinterpret_cast<const bf16x8*>(Bm + (size_t)(j0 + jc * 16 + lr) * DHEAD + ko);
    #pragma unroll
    for (int ic = 0; ic < 4; ++ic)
      #pragma unroll
      for (int jc = 0; jc < 4; ++jc)
        acc[ic][jc] = __builtin_amdgcn_mfma_f32_16x16x32_bf16(af[ic], bf[jc], acc[ic][jc], 0, 0, 0);
  }

  const float NLOG2E = -1.44269504088896340736f;
  __half* Wp = W + (size_t)pb * (T1 * T1);
  int ib = kg << 2;
  #pragma unroll
  for (int ic = 0; ic < 4; ++ic) {
    int i = i0 + ic * 16 + ib;
    #pragma unroll
    for (int jc = 0; jc < 4; ++jc) {
      int j = j0 + jc * 16 + lr;
      union { __half h[4]; uint2 u; } pk;
      #pragma unroll
      for (int r = 0; r < 4; ++r) {
        float d = 1.0f - acc[ic][jc][r];
        pk.h[r] = __float2half(exp2f(NLOG2E * d));
      }
      *reinterpret_cast<uint2*>(Wp + (size_t)j * T1 + i) = pk.u;
    }
  }
}

// ---------------- kernel 3: soft-DTW, exp domain, 2 waves x 4 rows/lane, shifted clock ----
// Structure identical to round 12 (absmax 0.0 proven). Round-13 fix is vmcnt ARITHMETIC:
// producer = 2 loads/column, so counted waits must be in LOADS not columns. PFD=32;
// group-top vmcnt(32) leaves 16 columns (32 loads) in flight and guarantees cols <=
// tb+15 landed (d7 needs tb+7, refills <= tb+15); the newest required load is 17 steps
// (~2 groups) old >> HBM latency — round 12's vmcnt(16) stalled ~an HBM round trip per
// group. Prologue vmcnt(48) (of 64 issued) -> cols 0..7 landed for RS_INIT.
// Margins @PFD=32: W-ring WAR: slot c rewritten at issue of col c+128 at local step
// c+96 > last ds_read of col c at c+55. Handoff: wave0 lane63 writes row-256 value
// (pre-renorm, 1-step delayed) to hval[col&127], group base to hbase[g&31]; published
// by lgkmcnt(0)+s_barrier; consumer group g1 (joint barrier 10+g1) reads cols written
// in wave0 group g1+8, complete by joint barrier g1+10 (exact). Barriers 81 = 81.
__global__ __launch_bounds__(128, 1) void k_dtw(const __half* __restrict__ W,
                                                float* __restrict__ res) {
  __shared__ __attribute__((aligned(16))) char ring[2 * WRING];
  __shared__ __attribute__((aligned(16))) float hval[RSLOTS];
  __shared__ float hbase[32];
  const int prob = blockIdx.x;
  const __half* Wp = W + (size_t)prob * (T1 * T1);
  const int tid  = threadIdx.x;
  const int lane = tid & 63;
  const int w    = __builtin_amdgcn_readfirstlane(tid >> 6);   // 0 or 1, wave-uniform

  const char* gbase = (const char*)Wp + (w << 9);   // wave's 512B slice base in column
  char* ringw = ring + (w << 16);

  float Va[4], Vb[4];
  #pragma unroll
  for (int r = 0; r < 4; ++r) { Va[r] = 0.f; Vb[r] = 0.f; }
  float B2 = 0.f, B2p = 0.f;       // per-lane base (log2 units, int-valued, exact)
  float cSave = 0.f;               // wave0 lane63: delayed handoff value (pre-renorm)
  float dgl0  = 0.f;               // wave1 lane0: saved diag (prev step's up)
  unsigned hw = 256;               // hval write byte offset for local step 0 (col -64)

  auto dppshr = [](float v) -> float {   // lane l <- lane l-1; lane 0 <- 0 (VALU only)
    return __int_as_float(__builtin_amdgcn_update_dpp(
        0, __float_as_int(v), 0x138 /*wave_shr:1*/, 0xF, 0xF, true));
  };

#define SCALEBITS(dexp) __uint_as_float( \
    (unsigned)(127 + (int)fminf(fmaxf((dexp), -120.f), 120.f)) << 23)

#define GLL4(GP, LP) __builtin_amdgcn_global_load_lds( \
    (const __attribute__((address_space(1))) void*)(GP), \
    (__attribute__((address_space(3))) void*)(LP), 4, 0, 0)

  // -------- producer prologue: issue cols 0..PFD-1 (2 loads each = 64 loads) --------
  #pragma unroll
  for (int c = 0; c < PFD; ++c) {
    const char* gp = gbase + ((size_t)c << 10);
    char* lp = ringw + ((unsigned)c << 9);
    GLL4(gp + (lane << 2), lp);
    GLL4(gp + 256 + (lane << 2), lp + 256);
  }
  asm volatile("s_waitcnt vmcnt(48)" ::: "memory");   // cols 0..7 landed (48 = 24 cols out)

  // consumer buffers for local steps 0..7 (lane-skewed slots!), persistent refill addrs
  uint2 d0, d1, d2, d3, d4, d5, d6, d7;
  unsigned va0, va1, va2, va3, va4, va5, va6, va7;
#define RS_INIT(K) do { \
    d##K = *reinterpret_cast<const uint2*>( \
        ringw + ((((unsigned)((K) - lane) & 127u) << 9) | (unsigned)(lane << 3))); \
    va##K = ((((unsigned)((K) + 8 - lane) & 127u) << 9) | (unsigned)(lane << 3)); \
  } while (0)
  RS_INIT(0); RS_INIT(1); RS_INIT(2); RS_INIT(3); RS_INIT(4); RS_INIT(5); RS_INIT(6);
#undef RS_INIT
  va7 = ((((unsigned)(7 - lane) & 127u) << 9) | (unsigned)(lane << 3));  // d7 at group top

#define DTW_STEP2(KK, VIN, VOUT, SDG, SEEDK, GUARD, ISW0) do {                \
    const int t_ = tb + (KK);                                                 \
    if (ISW0) {                      /* delayed handoff write at step top */  \
      if (lane == 63) {                                                       \
        *reinterpret_cast<float*>(reinterpret_cast<char*>(hval) + hw) = cSave;\
        if ((KK) == 0) hbase[(tb >> 3) & 31] = B2;                            \
      }                                                                       \
      hw = (hw + 4u) & 511u;                                                  \
    }                                                                         \
    float nbUp_ = dppshr(VIN[3]);            /* neighbor end of t-1 */        \
    float nbDg_ = dppshr(VOUT[3]);           /* neighbor end of t-2 */        \
    float up_ = nbUp_ * sUp;                                                  \
    float dg_ = nbDg_ * (SDG);                                                \
    if (!ISW0) {                             /* wave1 lane0: handoff path */  \
      float hup_ = hv[KK] * ((KK) == 0 ? sH0 : sH1);                          \
      up_ = (lane == 0) ? hup_ : up_;                                         \
      dg_ = (lane == 0) ? dgl0 : dg_;                                         \
      dgl0 = hup_;                                                            \
    }                                                                         \
    if (SEEDK) dg_ = (lane == 0) ? 1.0f : dg_;      /* E[0][0]=1 at t=0 */    \
    union { uint2 u; __half h[4]; } cv_; cv_.u = d##KK;                       \
    if ((KK) != 7) {                          /* refill: col t_+8-lane */     \
      d##KK = *reinterpret_cast<const uint2*>(ringw + va##KK);                \
      va##KK = (va##KK + 4096u) & (WRING - 1);                                \
    }                                                                         \
    { int cc_ = t_ + PFD; cc_ = cc_ > T1 - 1 ? T1 - 1 : cc_;                  \
      const char* gp_ = gbase + ((size_t)cc_ << 10);                          \
      char* lp_ = ringw + (((unsigned)cc_ & 127u) << 9);                      \
      GLL4(gp_ + (lane << 2), lp_);                                           \
      GLL4(gp_ + 256 + (lane << 2), lp_ + 256);                               \
    }                                                                         \
    float w0_ = __half2float(cv_.h[0]), w1_ = __half2float(cv_.h[1]);         \
    float w2_ = __half2float(cv_.h[2]), w3_ = __half2float(cv_.h[3]);         \
    bool act_ = true;                                                         \
    if (GUARD) { int j_ = t_ - lane; act_ = ((unsigned)j_ < (unsigned)T1); }  \
    if (act_) {                                                               \
      float c_ = fmaf(w0_, up_, w0_ * (dg_ + VIN[0]));  VOUT[0] = c_;         \
      c_ = fmaf(w1_, c_, w1_ * (VIN[0] + VIN[1]));      VOUT[1] = c_;         \
      c_ = fmaf(w2_, c_, w2_ * (VIN[1] + VIN[2]));      VOUT[2] = c_;         \
      c_ = fmaf(w3_, c_, w3_ * (VIN[2] + VIN[3]));      VOUT[3] = c_;         \
      if (ISW0) cSave = c_;                  /* pre-renorm handoff value */   \
      if ((KK) == 7) {                       /* exact pow2 renorm */          \
        float m_ = fmaxf(fmaxf(VOUT[0], VOUT[1]), fmaxf(VOUT[2], VOUT[3]));   \
        int e_ = (int)((__float_as_uint(m_) >> 23) & 0xFF) - 127;             \
        e_ = e_ < -126 ? -126 : (e_ > 126 ? 126 : e_);                        \
        float sc_ = __uint_as_float((unsigned)(127 - e_) << 23);              \
        VOUT[0] *= sc_; VOUT[1] *= sc_; VOUT[2] *= sc_; VOUT[3] *= sc_;       \
        if (!ISW0) dgl0 *= sc_;                                               \
        B2p = B2; B2 -= (float)e_;                                            \
      }                                                                       \
    }                                                                         \
  } while (0)

#define DTW_GROUP2(GUARD, SEED, ISW0) do {                                    \
    if (ISW0) { asm volatile("s_waitcnt lgkmcnt(0)" ::: "memory"); }          \
    __builtin_amdgcn_s_barrier();                                             \
    asm volatile("" ::: "memory");                                            \
    asm volatile("s_waitcnt vmcnt(32)" ::: "memory");  /* cols <= tb+15 in */ \
    d7 = *reinterpret_cast<const uint2*>(ringw + va7); /* col tb+7-lane */    \
    va7 = (va7 + 4096u) & (WRING - 1);                                        \
    float nbBn_ = dppshr(B2);                                                 \
    float nbBo_ = dppshr(B2p);                                                \
    float sUp  = SCALEBITS(B2 - nbBn_);                                       \
    float sDg0 = SCALEBITS(B2 - nbBo_);                                       \
    float hv[8] = {0.f,0.f,0.f,0.f,0.f,0.f,0.f,0.f};                          \
    float sH0 = 0.f, sH1 = 0.f;                                               \
    if (!ISW0) {                                                              \
      int c0_ = tb & 127;                        /* cols tb..tb+7 */          \
      f32x4 ha_ = *reinterpret_cast<const f32x4*>(hval + c0_);                \
      f32x4 hb_ = *reinterpret_cast<const f32x4*>(hval + c0_ + 4);            \
      hv[0]=ha_[0]; hv[1]=ha_[1]; hv[2]=ha_[2]; hv[3]=ha_[3];                 \
      hv[4]=hb_[0]; hv[5]=hb_[1]; hv[6]=hb_[2]; hv[7]=hb_[3];                 \
      int wg_ = (tb >> 3) + 8;                                                \
      sH1 = SCALEBITS(B2 - hbase[wg_ & 31]);        /* hv[1..7] base */       \
      sH0 = SCALEBITS(B2 - hbase[(wg_ - 1) & 31]);  /* hv[0]: KK7 pre-renorm */\
    }                                                                         \
    DTW_STEP2(0, Va, Vb, sDg0, SEED,  GUARD, ISW0);                           \
    DTW_STEP2(1, Vb, Va, sUp,  false, GUARD, ISW0);                           \
    DTW_STEP2(2, Va, Vb, sUp,  false, GUARD, ISW0);                           \
    DTW_STEP2(3, Vb, Va, sUp,  false, GUARD, ISW0);                           \
    DTW_STEP2(4, Va, Vb, sUp,  false, GUARD, ISW0);                           \
    DTW_STEP2(5, Vb, Va, sUp,  false, GUARD, ISW0);                           \
    DTW_STEP2(6, Va, Vb, sUp,  false, GUARD, ISW0);                           \
    DTW_STEP2(7, Vb, Va, sUp,  false, GUARD, ISW0);                           \
  } while (0)

  // 72 real groups per wave + NIDLE idle barriers; joint barrier count 81 = 81.
  if (w == 0) {
    { const int tb = 0; DTW_GROUP2(true, true, 1); }
    #pragma unroll 1
    for (int tb = 8; tb < 64; tb += 8)   DTW_GROUP2(true,  false, 1);
    #pragma unroll 1
    for (int tb = 64; tb < 568; tb += 8) DTW_GROUP2(false, false, 1);
    { const int tb = 568; DTW_GROUP2(true, false, 1); }
    #pragma unroll 1
    for (int i = 0; i < NIDLE; ++i) {    // publish last group's hval, then idle
      asm volatile("s_waitcnt lgkmcnt(0)" ::: "memory");
      __builtin_amdgcn_s_barrier();
      asm volatile("" ::: "memory");
    }
  } else {
    #pragma unroll 1
    for (int i = 0; i < NIDLE; ++i) {
      __builtin_amdgcn_s_barrier();
      asm volatile("" ::: "memory");
    }
    #pragma unroll 1
    for (int tb = 0; tb < 64; tb += 8)   DTW_GROUP2(true,  false, 0);
    #pragma unroll 1
    for (int tb = 64; tb < 568; tb += 8) DTW_GROUP2(false, false, 0);
    { const int tb = 568; DTW_GROUP2(true, false, 0); }
  }

  if (w == 1 && lane == 63) {
    // lane63 last active local step 574 (KK6 of tb=568) wrote Vb; R[512][512]:
    res[prob] = (B2 - log2f(Vb[3])) * 0.69314718055994530942f;
  }
#undef DTW_STEP2
#undef DTW_GROUP2
#undef SCALEBITS
#undef GLL4
}

// ---------------- kernel 4: combine ----------------
__global__ void k_combine(const float* __restrict__ res, float* __restrict__ out) {
  int b = threadIdx.x;
  if (b < NB) out[b] = res[b] - 0.5f * (res[NB + b] + res[2 * NB + b]);
}

extern "C" void kernel_launch(void* const* d_in, const int* in_sizes, int n_in,
                              void* d_out, int out_size, void* d_ws, size_t ws_size,
                              hipStream_t stream) {
  const float* x = (const float*)d_in[0];
  const float* y = (const float*)d_in[1];
  float* out = (float*)d_out;

  const size_t xb_off  = 0;
  const size_t yb_off  = (size_t)NB * T1 * DHEAD * sizeof(ushort);           // 2 MB
  const size_t W_off   = 2 * yb_off;                                          // 4 MB
  const size_t res_off = W_off + (size_t)3 * NB * T1 * T1 * sizeof(__half);   // +50.33 MB
  const size_t need    = res_off + NP * sizeof(float);

  if (ws_size < need) {
    hipMemsetAsync(d_out, 0xFF, (size_t)out_size * sizeof(float), stream);
    return;
  }

  ushort* xb  = (ushort*)((char*)d_ws + xb_off);
  ushort* yb  = (ushort*)((char*)d_ws + yb_off);
  __half* W   = (__half*)((char*)d_ws + W_off);
  float*  res = (float*)((char*)d_ws + res_off);

  hipLaunchKernelGGL(k_normalize, dim3(8192), dim3(256), 0, stream, x, y, xb, yb);
  hipLaunchKernelGGL(k_gemm_w, dim3(4, 4, 96), dim3(256), 0, stream, xb, yb, W);
  hipLaunchKernelGGL(k_dtw, dim3(NP), dim3(128), 0, stream, W, res);
  hipLaunchKernelGGL(k_combine, dim3(1), dim3(64), 0, stream, res, out);
}

// Round 15
// 92.274 us; speedup vs baseline: 2.1347x; 2.1293x over previous
//
#include <hip/hip_runtime.h>
#include <hip/hip_fp16.h>

#define T1 512
#define NB 32      // batches
#define NP 96      // 3 pairs * 32 batches
#define DHEAD 64

#define RSLOTS 128                 // LDS ring slots (1 KB column each) = 131072 B, pow2
#define RBYTES (RSLOTS * 1024)
#define PFD 32                     // producer prefetch distance (columns ahead)

typedef __attribute__((ext_vector_type(8))) short bf16x8;
typedef __attribute__((ext_vector_type(4))) float f32x4;
typedef __attribute__((ext_vector_type(4))) unsigned int u32x4;

// ---------------- kernel 1: row-normalize x,y -> bf16 ----------------
__global__ __launch_bounds__(256) void k_normalize(const float* __restrict__ x,
                                                   const float* __restrict__ y,
                                                   ushort* __restrict__ xb,
                                                   ushort* __restrict__ yb) {
  int wid  = threadIdx.x >> 6;
  int lane = threadIdx.x & 63;
  int row  = blockIdx.x * 4 + wid;          // 0 .. 32767
  const float* src; ushort* dst;
  if (row < NB * T1) { src = x + (size_t)row * DHEAD;            dst = xb + (size_t)row * DHEAD; }
  else { int r2 = row - NB * T1; src = y + (size_t)r2 * DHEAD;   dst = yb + (size_t)r2 * DHEAD; }
  float v = src[lane];
  float s = v * v;
  #pragma unroll
  for (int off = 32; off > 0; off >>= 1) s += __shfl_xor(s, off);
  float rn = 1.0f / fmaxf(sqrtf(s), 1e-12f);
  float o = v * rn;
  unsigned u = __float_as_uint(o);
  unsigned r = (u + 0x7fffu + ((u >> 16) & 1u)) >> 16;   // RNE to bf16
  dst[lane] = (ushort)r;
}

// ---------------- kernel 2: MFMA bf16 GEMM -> W[p][b][j][i] = exp(-(1-dot)) f16 ----------------
__global__ __launch_bounds__(256) void k_gemm_w(const ushort* __restrict__ xb,
                                                const ushort* __restrict__ yb,
                                                __half* __restrict__ W) {
  int pb = blockIdx.z;            // 0..95
  int p  = pb >> 5;               // 0:xy 1:xx 2:yy
  int b  = pb & 31;
  const ushort* A  = ((p == 2) ? yb : xb) + (size_t)b * T1 * DHEAD;  // i-side (M)
  const ushort* Bm = ((p == 1) ? xb : yb) + (size_t)b * T1 * DHEAD;  // j-side (N)

  int wid = threadIdx.x >> 6, lane = threadIdx.x & 63;
  int wm = wid >> 1, wn = wid & 1;
  int i0 = blockIdx.x * 128 + wm * 64;
  int j0 = blockIdx.y * 128 + wn * 64;
  int lr = lane & 15, kg = lane >> 4;

  f32x4 acc[4][4];
  #pragma unroll
  for (int ic = 0; ic < 4; ++ic)
    #pragma unroll
    for (int jc = 0; jc < 4; ++jc) acc[ic][jc] = (f32x4){0.f, 0.f, 0.f, 0.f};

  #pragma unroll
  for (int kk = 0; kk < 2; ++kk) {
    int ko = kk * 32 + kg * 8;
    bf16x8 af[4], bf[4];
    #pragma unroll
    for (int ic = 0; ic < 4; ++ic)
      af[ic] = *reinterpret_cast<const bf16x8*>(A + (size_t)(i0 + ic * 16 + lr) * DHEAD + ko);
    #pragma unroll
    for (int jc = 0; jc < 4; ++jc)
      bf[jc] = *reinterpret_cast<const bf16x8*>(Bm + (size_t)(j0 + jc * 16 + lr) * DHEAD + ko);
    #pragma unroll
    for (int ic = 0; ic < 4; ++ic)
      #pragma unroll
      for (int jc = 0; jc < 4; ++jc)
        acc[ic][jc] = __builtin_amdgcn_mfma_f32_16x16x32_bf16(af[ic], bf[jc], acc[ic][jc], 0, 0, 0);
  }

  const float NLOG2E = -1.44269504088896340736f;
  __half* Wp = W + (size_t)pb * (T1 * T1);
  int ib = kg << 2;
  #pragma unroll
  for (int ic = 0; ic < 4; ++ic) {
    int i = i0 + ic * 16 + ib;
    #pragma unroll
    for (int jc = 0; jc < 4; ++jc) {
      int j = j0 + jc * 16 + lr;
      union { __half h[4]; uint2 u; } pk;
      #pragma unroll
      for (int r = 0; r < 4; ++r) {
        float d = 1.0f - acc[ic][jc][r];
        pk.h[r] = __float2half(exp2f(NLOG2E * d));
      }
      *reinterpret_cast<uint2*>(Wp + (size_t)j * T1 + i) = pk.u;
    }
  }
}

// ---------------- kernel 3: soft-DTW, exp domain, skew-1, minimal bookkeeping ----------
// EXACT round-10 kernel (55.4 us proven) with ONE fix: the final readout register.
// Lane l owns DP rows 8l+1..8l+8; col j = t - lane at step t; 72 groups of 8 steps.
// DP math: chained FMA scan, exact pow2 renorm every 8 steps, group-hoisted base
// scales (2 DPP + 2 SCALEBITS per group), DPP wave_shr lane exchange (pure VALU).
// W feed: 128-slot LDS column ring, 1x global_load_lds(16B/lane) per column, PFD=32
// ahead, ONE counted vmcnt(16) per group (cols <= tb+15 landed; d7 needs tb+7).
// Guards: groups t<64 (pre-active lanes must not consume never-written LDS) and the
// final group (protects lane63 at t=575); middle 63 groups unguarded.
// READOUT FIX: lane63's last ACTIVE step is t=574 (KK6, even -> writes Vb); t=575
// (KK7) is guarded off and its renorm skipped, so B2 is consistent with Vb. Round-10
// read Va[7] = t=573 = column 510 -> R[512][511], the absmax-2.0 source. Read Vb[7].
__global__ __launch_bounds__(64, 1) void k_dtw(const __half* __restrict__ W,
                                               float* __restrict__ res) {
  __shared__ __attribute__((aligned(16))) char ring[RBYTES];
  const int prob = blockIdx.x;
  const __half* Wp = W + (size_t)prob * (T1 * T1);
  const int lane = threadIdx.x;

  float Va[8], Vb[8];
  #pragma unroll
  for (int r = 0; r < 8; ++r) { Va[r] = 0.f; Vb[r] = 0.f; }
  float B2 = 0.f, B2p = 0.f;
  const float dgSeed = (lane == 0) ? 1.0f : 0.0f;

  auto dppshr = [](float v) -> float {   // lane l <- lane l-1; lane 0 <- 0 (VALU only)
    return __int_as_float(__builtin_amdgcn_update_dpp(
        0, __float_as_int(v), 0x138 /*wave_shr:1*/, 0xF, 0xF, true));
  };

  // producer state: per-lane global src ptr (col 32 onward) + uniform LDS slot offset
  const char* gsrc = (const char*)Wp + (size_t)PFD * 1024 + (lane << 4);
  unsigned lslot = (PFD << 10) & (RBYTES - 1);

  // prologue: issue cols 0..31
  #pragma unroll
  for (int c = 0; c < PFD; ++c) {
    const __half* gp = Wp + ((size_t)c << 9) + (lane << 3);
    __builtin_amdgcn_global_load_lds(
        (const __attribute__((address_space(1))) void*)gp,
        (__attribute__((address_space(3))) void*)(ring + ((unsigned)(c << 10))), 16, 0, 0);
  }
  asm volatile("s_waitcnt vmcnt(24)" ::: "memory");   // cols 0..7 landed

  u32x4 d0, d1, d2, d3, d4, d5, d6, d7;
  unsigned va0, va1, va2, va3, va4, va5, va6, va7;
#define RS_INIT(K) do { \
    d##K = *reinterpret_cast<const u32x4*>( \
        ring + ((((unsigned)(K - lane) & 127u) << 10) | (unsigned)(lane << 4))); \
    va##K = ((((unsigned)(8 + K - lane) & 127u) << 10) | (unsigned)(lane << 4)); \
  } while (0)
  RS_INIT(0); RS_INIT(1); RS_INIT(2); RS_INIT(3);
  RS_INIT(4); RS_INIT(5); RS_INIT(6); RS_INIT(7);
#undef RS_INIT

#define DTW_STEP(KK, VIN, VOUT, SDG, SEEDK, GUARD) do {                       \
    const int t_ = tb + (KK);                                                 \
    float nbUp_ = dppshr(VIN[7]);            /* neighbor end of t-1 */        \
    float nbDg_ = dppshr(VOUT[7]);           /* neighbor end of t-2 */        \
    float up_ = nbUp_ * sUp;                                                  \
    float dg_ = nbDg_ * (SDG);                                                \
    if (SEEDK) dg_ = dgSeed;                                                  \
    union { u32x4 u; __half h[8]; } cv_; cv_.u = d##KK;                       \
    d##KK = *reinterpret_cast<const u32x4*>(ring + va##KK);  /* col t_+8 */   \
    va##KK = (va##KK + 8192u) & (RBYTES - 1);                                 \
    __builtin_amdgcn_global_load_lds(                        /* col t_+32 */  \
        (const __attribute__((address_space(1))) void*)gsrc,                  \
        (__attribute__((address_space(3))) void*)(ring + lslot), 16, 0, 0);   \
    lslot = (lslot + 1024u) & (RBYTES - 1);                                   \
    gsrc += ((t_ + PFD) < T1 - 1) ? 1024 : 0;  /* clamp at col 511 */         \
    float wv_[8];                                                             \
    _Pragma("unroll")                                                         \
    for (int r = 0; r < 8; ++r) wv_[r] = __half2float(cv_.h[r]);              \
    bool act_ = true;                                                         \
    if (GUARD) { int j_ = t_ - lane; act_ = ((unsigned)j_ < (unsigned)T1); }  \
    if (act_) {                                                               \
      float c_ = fmaf(wv_[0], up_, wv_[0] * (dg_ + VIN[0]));                  \
      VOUT[0] = c_;                                                           \
      _Pragma("unroll")                                                       \
      for (int r = 1; r < 8; ++r) {                                           \
        c_ = fmaf(wv_[r], c_, wv_[r] * (VIN[r-1] + VIN[r]));                  \
        VOUT[r] = c_;                                                         \
      }                                                                       \
      if ((KK) == 7) {                       /* exact pow2 renorm */          \
        float m_ = fmaxf(fmaxf(fmaxf(VOUT[0],VOUT[1]),fmaxf(VOUT[2],VOUT[3])),\
                         fmaxf(fmaxf(VOUT[4],VOUT[5]),fmaxf(VOUT[6],VOUT[7])));\
        int e_ = (int)((__float_as_uint(m_) >> 23) & 0xFF) - 127;             \
        e_ = e_ < -126 ? -126 : (e_ > 126 ? 126 : e_);                        \
        float sc_ = __uint_as_float((unsigned)(127 - e_) << 23);              \
        _Pragma("unroll")                                                     \
        for (int r = 0; r < 8; ++r) VOUT[r] *= sc_;                           \
        B2p = B2; B2 -= (float)e_;                                            \
      }                                                                       \
    }                                                                         \
  } while (0)

#define DTW_GROUP(GUARD, SEED) do {                                           \
    asm volatile("s_waitcnt vmcnt(16)" ::: "memory");  /* cols <= tb+15 */    \
    float nbBn_ = dppshr(B2);                /* neighbor base, post-renorm */ \
    float nbBo_ = dppshr(B2p);               /* neighbor base, pre-renorm  */ \
    float sUp  = __uint_as_float(                                             \
        (unsigned)(127 + (int)fminf(fmaxf(B2 - nbBn_, -120.f), 120.f)) << 23);\
    float sDg0 = __uint_as_float(                                             \
        (unsigned)(127 + (int)fminf(fmaxf(B2 - nbBo_, -120.f), 120.f)) << 23);\
    DTW_STEP(0, Va, Vb, sDg0, SEED, GUARD);                                   \
    DTW_STEP(1, Vb, Va, sUp, false, GUARD);                                   \
    DTW_STEP(2, Va, Vb, sUp, false, GUARD);                                   \
    DTW_STEP(3, Vb, Va, sUp, false, GUARD);                                   \
    DTW_STEP(4, Va, Vb, sUp, false, GUARD);                                   \
    DTW_STEP(5, Vb, Va, sUp, false, GUARD);                                   \
    DTW_STEP(6, Va, Vb, sUp, false, GUARD);                                   \
    DTW_STEP(7, Vb, Va, sUp, false, GUARD);                                   \
  } while (0)

  { const int tb = 0; DTW_GROUP(true, true); }          // seed group (guarded)
  #pragma unroll 1
  for (int tb = 8; tb < 64; tb += 8)  DTW_GROUP(true, false);   // pre-active era
  #pragma unroll 1
  for (int tb = 64; tb < 568; tb += 8) DTW_GROUP(false, false); // unguarded middle
  { const int tb = 568; DTW_GROUP(true, false); }       // final group (guarded)

  if (lane == 63) {
    // lane63's last ACTIVE step t=574 (KK6, even -> wrote Vb): col 511 = R[512][512].
    res[prob] = (B2 - log2f(Vb[7])) * 0.69314718055994530942f;
  }
#undef DTW_STEP
#undef DTW_GROUP
}

// ---------------- kernel 4: combine ----------------
__global__ void k_combine(const float* __restrict__ res, float* __restrict__ out) {
  int b = threadIdx.x;
  if (b < NB) out[b] = res[b] - 0.5f * (res[NB + b] + res[2 * NB + b]);
}

extern "C" void kernel_launch(void* const* d_in, const int* in_sizes, int n_in,
                              void* d_out, int out_size, void* d_ws, size_t ws_size,
                              hipStream_t stream) {
  const float* x = (const float*)d_in[0];
  const float* y = (const float*)d_in[1];
  float* out = (float*)d_out;

  const size_t xb_off  = 0;
  const size_t yb_off  = (size_t)NB * T1 * DHEAD * sizeof(ushort);           // 2 MB
  const size_t W_off   = 2 * yb_off;                                          // 4 MB
  const size_t res_off = W_off + (size_t)3 * NB * T1 * T1 * sizeof(__half);   // +50.33 MB
  const size_t need    = res_off + NP * sizeof(float);

  if (ws_size < need) {
    hipMemsetAsync(d_out, 0xFF, (size_t)out_size * sizeof(float), stream);
    return;
  }

  ushort* xb  = (ushort*)((char*)d_ws + xb_off);
  ushort* yb  = (ushort*)((char*)d_ws + yb_off);
  __half* W   = (__half*)((char*)d_ws + W_off);
  float*  res = (float*)((char*)d_ws + res_off);

  hipLaunchKernelGGL(k_normalize, dim3(8192), dim3(256), 0, stream, x, y, xb, yb);
  hipLaunchKernelGGL(k_gemm_w, dim3(4, 4, 96), dim3(256), 0, stream, xb, yb, W);
  hipLaunchKernelGGL(k_dtw, dim3(NP), dim3(64), 0, stream, W, res);
  hipLaunchKernelGGL(k_combine, dim3(1), dim3(64), 0, stream, res, out);
}

// Round 16
// 85.309 us; speedup vs baseline: 2.3090x; 1.0816x over previous
//
#include <hip/hip_runtime.h>
#include <hip/hip_fp16.h>

#define T1 512
#define NB 32      // batches
#define NP 96      // 3 pairs * 32 batches
#define DHEAD 64

#define RSLOTS 128                 // LDS ring slots (1 KB column each) = 131072 B, pow2
#define RBYTES (RSLOTS * 1024)
#define PFD 32                     // producer prefetch distance (columns ahead)

typedef __attribute__((ext_vector_type(8))) short bf16x8;
typedef __attribute__((ext_vector_type(4))) float f32x4;
typedef __attribute__((ext_vector_type(4))) unsigned int u32x4;

// ---------------- kernel 1: row-normalize x,y -> bf16 ----------------
__global__ __launch_bounds__(256) void k_normalize(const float* __restrict__ x,
                                                   const float* __restrict__ y,
                                                   ushort* __restrict__ xb,
                                                   ushort* __restrict__ yb) {
  int wid  = threadIdx.x >> 6;
  int lane = threadIdx.x & 63;
  int row  = blockIdx.x * 4 + wid;          // 0 .. 32767
  const float* src; ushort* dst;
  if (row < NB * T1) { src = x + (size_t)row * DHEAD;            dst = xb + (size_t)row * DHEAD; }
  else { int r2 = row - NB * T1; src = y + (size_t)r2 * DHEAD;   dst = yb + (size_t)r2 * DHEAD; }
  float v = src[lane];
  float s = v * v;
  #pragma unroll
  for (int off = 32; off > 0; off >>= 1) s += __shfl_xor(s, off);
  float rn = 1.0f / fmaxf(sqrtf(s), 1e-12f);
  float o = v * rn;
  unsigned u = __float_as_uint(o);
  unsigned r = (u + 0x7fffu + ((u >> 16) & 1u)) >> 16;   // RNE to bf16
  dst[lane] = (ushort)r;
}

// ---------------- kernel 2: MFMA bf16 GEMM -> W[p][b][j][i] = exp(-(1-dot)) f16 ----------------
// Round-16 change: LDS-staged epilogue. The direct MFMA-layout store wrote 8B/lane at
// 1KB stride (50% sector waste -> ~2x DRAM write traffic). Now: stage the 128x128 f16
// tile in LDS (row stride 264B: +8B pad keeps b128 reads <=2-way bank-aliased = free),
// __syncthreads, then 256 threads store 16B each -> 256 contiguous B per W row (full
// 64B-sector utilization). W values bit-identical.
__global__ __launch_bounds__(256) void k_gemm_w(const ushort* __restrict__ xb,
                                                const ushort* __restrict__ yb,
                                                __half* __restrict__ W) {
  __shared__ __attribute__((aligned(16))) __half blk[128][132];   // 33792 B
  int pb = blockIdx.z;            // 0..95
  int p  = pb >> 5;               // 0:xy 1:xx 2:yy
  int b  = pb & 31;
  const ushort* A  = ((p == 2) ? yb : xb) + (size_t)b * T1 * DHEAD;  // i-side (M)
  const ushort* Bm = ((p == 1) ? xb : yb) + (size_t)b * T1 * DHEAD;  // j-side (N)

  int wid = threadIdx.x >> 6, lane = threadIdx.x & 63;
  int wm = wid >> 1, wn = wid & 1;
  int i0b = blockIdx.x * 128, j0b = blockIdx.y * 128;
  int i0 = i0b + wm * 64;
  int j0 = j0b + wn * 64;
  int lr = lane & 15, kg = lane >> 4;

  f32x4 acc[4][4];
  #pragma unroll
  for (int ic = 0; ic < 4; ++ic)
    #pragma unroll
    for (int jc = 0; jc < 4; ++jc) acc[ic][jc] = (f32x4){0.f, 0.f, 0.f, 0.f};

  #pragma unroll
  for (int kk = 0; kk < 2; ++kk) {
    int ko = kk * 32 + kg * 8;
    bf16x8 af[4], bf[4];
    #pragma unroll
    for (int ic = 0; ic < 4; ++ic)
      af[ic] = *reinterpret_cast<const bf16x8*>(A + (size_t)(i0 + ic * 16 + lr) * DHEAD + ko);
    #pragma unroll
    for (int jc = 0; jc < 4; ++jc)
      bf[jc] = *reinterpret_cast<const bf16x8*>(Bm + (size_t)(j0 + jc * 16 + lr) * DHEAD + ko);
    #pragma unroll
    for (int ic = 0; ic < 4; ++ic)
      #pragma unroll
      for (int jc = 0; jc < 4; ++jc)
        acc[ic][jc] = __builtin_amdgcn_mfma_f32_16x16x32_bf16(af[ic], bf[jc], acc[ic][jc], 0, 0, 0);
  }

  // epilogue pass 1: exp + pack, stage into LDS at [local j][local i]
  const float NLOG2E = -1.44269504088896340736f;
  #pragma unroll
  for (int ic = 0; ic < 4; ++ic) {
    int il = wm * 64 + ic * 16 + (kg << 2);      // local i, multiple of 4 halfs (8B)
    #pragma unroll
    for (int jc = 0; jc < 4; ++jc) {
      int jl = wn * 64 + jc * 16 + lr;           // local j
      union { __half h[4]; uint2 u; } pk;
      #pragma unroll
      for (int r = 0; r < 4; ++r) {
        float d = 1.0f - acc[ic][jc][r];
        pk.h[r] = __float2half(exp2f(NLOG2E * d));
      }
      *reinterpret_cast<uint2*>(&blk[jl][il]) = pk.u;
    }
  }
  __syncthreads();

  // epilogue pass 2: coalesced store — 16 lanes x 16B = 256 contiguous B per W row
  __half* Wp = W + (size_t)pb * (T1 * T1);
  int tr = threadIdx.x >> 4;        // 0..15  (row within 16-row slab)
  int tc = threadIdx.x & 15;        // 0..15  (16B chunk within row)
  #pragma unroll
  for (int q = 0; q < 8; ++q) {
    int j = q * 16 + tr;
    u32x4 v = *reinterpret_cast<const u32x4*>(&blk[j][tc << 3]);
    *reinterpret_cast<u32x4*>(Wp + (size_t)(j0b + j) * T1 + i0b + (tc << 3)) = v;
  }
}

// ---------------- kernel 3: soft-DTW, exp domain, skew-1, minimal bookkeeping ----------
// UNCHANGED from round 15 (55.4 us, absmax 0.0 proven).
// Lane l owns DP rows 8l+1..8l+8; col j = t - lane at step t; 72 groups of 8 steps.
// DP math: chained FMA scan, exact pow2 renorm every 8 steps, group-hoisted base
// scales (2 DPP + 2 SCALEBITS per group), DPP wave_shr lane exchange (pure VALU).
// W feed: 128-slot LDS column ring, 1x global_load_lds(16B/lane) per column, PFD=32
// ahead, ONE counted vmcnt(16) per group (cols <= tb+15 landed; d7 needs tb+7).
// Guards: groups t<64 and the final group; middle 63 groups unguarded.
// Readout: lane63's last ACTIVE step t=574 (KK6, even -> writes Vb) -> read Vb[7].
__global__ __launch_bounds__(64, 1) void k_dtw(const __half* __restrict__ W,
                                               float* __restrict__ res) {
  __shared__ __attribute__((aligned(16))) char ring[RBYTES];
  const int prob = blockIdx.x;
  const __half* Wp = W + (size_t)prob * (T1 * T1);
  const int lane = threadIdx.x;

  float Va[8], Vb[8];
  #pragma unroll
  for (int r = 0; r < 8; ++r) { Va[r] = 0.f; Vb[r] = 0.f; }
  float B2 = 0.f, B2p = 0.f;
  const float dgSeed = (lane == 0) ? 1.0f : 0.0f;

  auto dppshr = [](float v) -> float {   // lane l <- lane l-1; lane 0 <- 0 (VALU only)
    return __int_as_float(__builtin_amdgcn_update_dpp(
        0, __float_as_int(v), 0x138 /*wave_shr:1*/, 0xF, 0xF, true));
  };

  // producer state: per-lane global src ptr (col 32 onward) + uniform LDS slot offset
  const char* gsrc = (const char*)Wp + (size_t)PFD * 1024 + (lane << 4);
  unsigned lslot = (PFD << 10) & (RBYTES - 1);

  // prologue: issue cols 0..31
  #pragma unroll
  for (int c = 0; c < PFD; ++c) {
    const __half* gp = Wp + ((size_t)c << 9) + (lane << 3);
    __builtin_amdgcn_global_load_lds(
        (const __attribute__((address_space(1))) void*)gp,
        (__attribute__((address_space(3))) void*)(ring + ((unsigned)(c << 10))), 16, 0, 0);
  }
  asm volatile("s_waitcnt vmcnt(24)" ::: "memory");   // cols 0..7 landed

  u32x4 d0, d1, d2, d3, d4, d5, d6, d7;
  unsigned va0, va1, va2, va3, va4, va5, va6, va7;
#define RS_INIT(K) do { \
    d##K = *reinterpret_cast<const u32x4*>( \
        ring + ((((unsigned)(K - lane) & 127u) << 10) | (unsigned)(lane << 4))); \
    va##K = ((((unsigned)(8 + K - lane) & 127u) << 10) | (unsigned)(lane << 4)); \
  } while (0)
  RS_INIT(0); RS_INIT(1); RS_INIT(2); RS_INIT(3);
  RS_INIT(4); RS_INIT(5); RS_INIT(6); RS_INIT(7);
#undef RS_INIT

#define DTW_STEP(KK, VIN, VOUT, SDG, SEEDK, GUARD) do {                       \
    const int t_ = tb + (KK);                                                 \
    float nbUp_ = dppshr(VIN[7]);            /* neighbor end of t-1 */        \
    float nbDg_ = dppshr(VOUT[7]);           /* neighbor end of t-2 */        \
    float up_ = nbUp_ * sUp;                                                  \
    float dg_ = nbDg_ * (SDG);                                                \
    if (SEEDK) dg_ = dgSeed;                                                  \
    union { u32x4 u; __half h[8]; } cv_; cv_.u = d##KK;                       \
    d##KK = *reinterpret_cast<const u32x4*>(ring + va##KK);  /* col t_+8 */   \
    va##KK = (va##KK + 8192u) & (RBYTES - 1);                                 \
    __builtin_amdgcn_global_load_lds(                        /* col t_+32 */  \
        (const __attribute__((address_space(1))) void*)gsrc,                  \
        (__attribute__((address_space(3))) void*)(ring + lslot), 16, 0, 0);   \
    lslot = (lslot + 1024u) & (RBYTES - 1);                                   \
    gsrc += ((t_ + PFD) < T1 - 1) ? 1024 : 0;  /* clamp at col 511 */         \
    float wv_[8];                                                             \
    _Pragma("unroll")                                                         \
    for (int r = 0; r < 8; ++r) wv_[r] = __half2float(cv_.h[r]);              \
    bool act_ = true;                                                         \
    if (GUARD) { int j_ = t_ - lane; act_ = ((unsigned)j_ < (unsigned)T1); }  \
    if (act_) {                                                               \
      float c_ = fmaf(wv_[0], up_, wv_[0] * (dg_ + VIN[0]));                  \
      VOUT[0] = c_;                                                           \
      _Pragma("unroll")                                                       \
      for (int r = 1; r < 8; ++r) {                                           \
        c_ = fmaf(wv_[r], c_, wv_[r] * (VIN[r-1] + VIN[r]));                  \
        VOUT[r] = c_;                                                         \
      }                                                                       \
      if ((KK) == 7) {                       /* exact pow2 renorm */          \
        float m_ = fmaxf(fmaxf(fmaxf(VOUT[0],VOUT[1]),fmaxf(VOUT[2],VOUT[3])),\
                         fmaxf(fmaxf(VOUT[4],VOUT[5]),fmaxf(VOUT[6],VOUT[7])));\
        int e_ = (int)((__float_as_uint(m_) >> 23) & 0xFF) - 127;             \
        e_ = e_ < -126 ? -126 : (e_ > 126 ? 126 : e_);                        \
        float sc_ = __uint_as_float((unsigned)(127 - e_) << 23);              \
        _Pragma("unroll")                                                     \
        for (int r = 0; r < 8; ++r) VOUT[r] *= sc_;                           \
        B2p = B2; B2 -= (float)e_;                                            \
      }                                                                       \
    }                                                                         \
  } while (0)

#define DTW_GROUP(GUARD, SEED) do {                                           \
    asm volatile("s_waitcnt vmcnt(16)" ::: "memory");  /* cols <= tb+15 */    \
    float nbBn_ = dppshr(B2);                /* neighbor base, post-renorm */ \
    float nbBo_ = dppshr(B2p);               /* neighbor base, pre-renorm  */ \
    float sUp  = __uint_as_float(                                             \
        (unsigned)(127 + (int)fminf(fmaxf(B2 - nbBn_, -120.f), 120.f)) << 23);\
    float sDg0 = __uint_as_float(                                             \
        (unsigned)(127 + (int)fminf(fmaxf(B2 - nbBo_, -120.f), 120.f)) << 23);\
    DTW_STEP(0, Va, Vb, sDg0, SEED, GUARD);                                   \
    DTW_STEP(1, Vb, Va, sUp, false, GUARD);                                   \
    DTW_STEP(2, Va, Vb, sUp, false, GUARD);                                   \
    DTW_STEP(3, Vb, Va, sUp, false, GUARD);                                   \
    DTW_STEP(4, Va, Vb, sUp, false, GUARD);                                   \
    DTW_STEP(5, Vb, Va, sUp, false, GUARD);                                   \
    DTW_STEP(6, Va, Vb, sUp, false, GUARD);                                   \
    DTW_STEP(7, Vb, Va, sUp, false, GUARD);                                   \
  } while (0)

  { const int tb = 0; DTW_GROUP(true, true); }          // seed group (guarded)
  #pragma unroll 1
  for (int tb = 8; tb < 64; tb += 8)  DTW_GROUP(true, false);   // pre-active era
  #pragma unroll 1
  for (int tb = 64; tb < 568; tb += 8) DTW_GROUP(false, false); // unguarded middle
  { const int tb = 568; DTW_GROUP(true, false); }       // final group (guarded)

  if (lane == 63) {
    // lane63's last ACTIVE step t=574 (KK6, even -> wrote Vb): col 511 = R[512][512].
    res[prob] = (B2 - log2f(Vb[7])) * 0.69314718055994530942f;
  }
#undef DTW_STEP
#undef DTW_GROUP
}

// ---------------- kernel 4: combine ----------------
__global__ void k_combine(const float* __restrict__ res, float* __restrict__ out) {
  int b = threadIdx.x;
  if (b < NB) out[b] = res[b] - 0.5f * (res[NB + b] + res[2 * NB + b]);
}

extern "C" void kernel_launch(void* const* d_in, const int* in_sizes, int n_in,
                              void* d_out, int out_size, void* d_ws, size_t ws_size,
                              hipStream_t stream) {
  const float* x = (const float*)d_in[0];
  const float* y = (const float*)d_in[1];
  float* out = (float*)d_out;

  const size_t xb_off  = 0;
  const size_t yb_off  = (size_t)NB * T1 * DHEAD * sizeof(ushort);           // 2 MB
  const size_t W_off   = 2 * yb_off;                                          // 4 MB
  const size_t res_off = W_off + (size_t)3 * NB * T1 * T1 * sizeof(__half);   // +50.33 MB
  const size_t need    = res_off + NP * sizeof(float);

  if (ws_size < need) {
    hipMemsetAsync(d_out, 0xFF, (size_t)out_size * sizeof(float), stream);
    return;
  }

  ushort* xb  = (ushort*)((char*)d_ws + xb_off);
  ushort* yb  = (ushort*)((char*)d_ws + yb_off);
  __half* W   = (__half*)((char*)d_ws + W_off);
  float*  res = (float*)((char*)d_ws + res_off);

  hipLaunchKernelGGL(k_normalize, dim3(8192), dim3(256), 0, stream, x, y, xb, yb);
  hipLaunchKernelGGL(k_gemm_w, dim3(4, 4, 96), dim3(256), 0, stream, xb, yb, W);
  hipLaunchKernelGGL(k_dtw, dim3(NP), dim3(64), 0, stream, W, res);
  hipLaunchKernelGGL(k_combine, dim3(1), dim3(64), 0, stream, res, out);
}

// Round 17
// 84.297 us; speedup vs baseline: 2.3367x; 1.0120x over previous
//
#include <hip/hip_runtime.h>
#include <hip/hip_fp16.h>

#define T1 512
#define NB 32      // batches
#define NP 96      // 3 pairs * 32 batches
#define DHEAD 64

#define RSLOTS 128                 // LDS ring slots (1 KB column each) = 131072 B, pow2
#define RBYTES (RSLOTS * 1024)
#define PFD 32                     // producer prefetch distance (columns ahead)

typedef __attribute__((ext_vector_type(8))) short bf16x8;
typedef __attribute__((ext_vector_type(4))) float f32x4;
typedef __attribute__((ext_vector_type(4))) unsigned int u32x4;

// ---------------- kernel 1: row-normalize x,y -> bf16 ----------------
__global__ __launch_bounds__(256) void k_normalize(const float* __restrict__ x,
                                                   const float* __restrict__ y,
                                                   ushort* __restrict__ xb,
                                                   ushort* __restrict__ yb) {
  int wid  = threadIdx.x >> 6;
  int lane = threadIdx.x & 63;
  int row  = blockIdx.x * 4 + wid;          // 0 .. 32767
  const float* src; ushort* dst;
  if (row < NB * T1) { src = x + (size_t)row * DHEAD;            dst = xb + (size_t)row * DHEAD; }
  else { int r2 = row - NB * T1; src = y + (size_t)r2 * DHEAD;   dst = yb + (size_t)r2 * DHEAD; }
  float v = src[lane];
  float s = v * v;
  #pragma unroll
  for (int off = 32; off > 0; off >>= 1) s += __shfl_xor(s, off);
  float rn = 1.0f / fmaxf(sqrtf(s), 1e-12f);
  float o = v * rn;
  unsigned u = __float_as_uint(o);
  unsigned r = (u + 0x7fffu + ((u >> 16) & 1u)) >> 16;   // RNE to bf16
  dst[lane] = (ushort)r;
}

// ---------------- kernel 2: MFMA bf16 GEMM -> W[p][b][j][i] = exp(-(1-dot)) f16 ----------------
// LDS-staged epilogue (round 16, proven): stage 128x128 f16 tile in LDS (row stride
// 264B pad -> <=2-way bank aliasing = free), then 256 threads store 16B each = 256
// contiguous B per W row (full 64B-sector utilization).
__global__ __launch_bounds__(256) void k_gemm_w(const ushort* __restrict__ xb,
                                                const ushort* __restrict__ yb,
                                                __half* __restrict__ W) {
  __shared__ __attribute__((aligned(16))) __half blk[128][132];   // 33792 B
  int pb = blockIdx.z;            // 0..95
  int p  = pb >> 5;               // 0:xy 1:xx 2:yy
  int b  = pb & 31;
  const ushort* A  = ((p == 2) ? yb : xb) + (size_t)b * T1 * DHEAD;  // i-side (M)
  const ushort* Bm = ((p == 1) ? xb : yb) + (size_t)b * T1 * DHEAD;  // j-side (N)

  int wid = threadIdx.x >> 6, lane = threadIdx.x & 63;
  int wm = wid >> 1, wn = wid & 1;
  int i0b = blockIdx.x * 128, j0b = blockIdx.y * 128;
  int i0 = i0b + wm * 64;
  int j0 = j0b + wn * 64;
  int lr = lane & 15, kg = lane >> 4;

  f32x4 acc[4][4];
  #pragma unroll
  for (int ic = 0; ic < 4; ++ic)
    #pragma unroll
    for (int jc = 0; jc < 4; ++jc) acc[ic][jc] = (f32x4){0.f, 0.f, 0.f, 0.f};

  #pragma unroll
  for (int kk = 0; kk < 2; ++kk) {
    int ko = kk * 32 + kg * 8;
    bf16x8 af[4], bf[4];
    #pragma unroll
    for (int ic = 0; ic < 4; ++ic)
      af[ic] = *reinterpret_cast<const bf16x8*>(A + (size_t)(i0 + ic * 16 + lr) * DHEAD + ko);
    #pragma unroll
    for (int jc = 0; jc < 4; ++jc)
      bf[jc] = *reinterpret_cast<const bf16x8*>(Bm + (size_t)(j0 + jc * 16 + lr) * DHEAD + ko);
    #pragma unroll
    for (int ic = 0; ic < 4; ++ic)
      #pragma unroll
      for (int jc = 0; jc < 4; ++jc)
        acc[ic][jc] = __builtin_amdgcn_mfma_f32_16x16x32_bf16(af[ic], bf[jc], acc[ic][jc], 0, 0, 0);
  }

  // epilogue pass 1: exp + pack, stage into LDS at [local j][local i]
  const float NLOG2E = -1.44269504088896340736f;
  #pragma unroll
  for (int ic = 0; ic < 4; ++ic) {
    int il = wm * 64 + ic * 16 + (kg << 2);      // local i, multiple of 4 halfs (8B)
    #pragma unroll
    for (int jc = 0; jc < 4; ++jc) {
      int jl = wn * 64 + jc * 16 + lr;           // local j
      union { __half h[4]; uint2 u; } pk;
      #pragma unroll
      for (int r = 0; r < 4; ++r) {
        float d = 1.0f - acc[ic][jc][r];
        pk.h[r] = __float2half(exp2f(NLOG2E * d));
      }
      *reinterpret_cast<uint2*>(&blk[jl][il]) = pk.u;
    }
  }
  __syncthreads();

  // epilogue pass 2: coalesced store — 16 lanes x 16B = 256 contiguous B per W row
  __half* Wp = W + (size_t)pb * (T1 * T1);
  int tr = threadIdx.x >> 4;        // 0..15  (row within 16-row slab)
  int tc = threadIdx.x & 15;        // 0..15  (16B chunk within row)
  #pragma unroll
  for (int q = 0; q < 8; ++q) {
    int j = q * 16 + tr;
    u32x4 v = *reinterpret_cast<const u32x4*>(&blk[j][tc << 3]);
    *reinterpret_cast<u32x4*>(Wp + (size_t)(j0b + j) * T1 + i0b + (tc << 3)) = v;
  }
}

// ---------------- kernel 3: soft-DTW, exp domain, skew-1, 16-step groups ----------
// Round-17 changes vs the proven round-15/16 kernel (same structure, same indices):
//  (1) Producer addressing saddr-friendly: uniform size_t colOff (SALU evolution,
//      s_cselect clamp) + constant per-lane laneOff — removes the per-lane 64-bit
//      VALU pointer arithmetic from every step.
//  (2) Groups of 16 steps, renorm at KK15 only (exact pow2 renorm is bit-exact at any
//      frequency; range drift <= +-46 bits << f32 range). One scale-block per 16 steps
//      (was per 8) and a longer unroll window for cross-step chain-latency hiding.
//      Two counted waits per group: vmcnt(16) at top (cols <= tb+15 landed, covers
//      KK0-7 refills) and vmcnt(16) mid (cols <= tb+23, covers KK8-15 refills).
// Invariants preserved: VOUT[7] at step top = end of t-2; KK0 diag uses pre-renorm
// base B2p, KK1-15 use current base; guards t<64 (groups 0-3) + final group; readout
// Vb[7] (lane63 last active t=574 = KK14, even -> Vb).
__global__ __launch_bounds__(64, 1) void k_dtw(const __half* __restrict__ W,
                                               float* __restrict__ res) {
  __shared__ __attribute__((aligned(16))) char ring[RBYTES];
  const int prob = blockIdx.x;
  const __half* Wp = W + (size_t)prob * (T1 * T1);
  const int lane = threadIdx.x;

  float Va[8], Vb[8];
  #pragma unroll
  for (int r = 0; r < 8; ++r) { Va[r] = 0.f; Vb[r] = 0.f; }
  float B2 = 0.f, B2p = 0.f;
  const float dgSeed = (lane == 0) ? 1.0f : 0.0f;

  auto dppshr = [](float v) -> float {   // lane l <- lane l-1; lane 0 <- 0 (VALU only)
    return __int_as_float(__builtin_amdgcn_update_dpp(
        0, __float_as_int(v), 0x138 /*wave_shr:1*/, 0xF, 0xF, true));
  };

#define SCALEBITS(dexp) __uint_as_float( \
    (unsigned)(127 + (int)fminf(fmaxf((dexp), -120.f), 120.f)) << 23)

  // producer: uniform column byte offset (SALU) + constant per-lane byte offset
  const char* gW = (const char*)Wp;
  const unsigned laneOff = (unsigned)(lane << 4);   // 16 B/lane slice
  size_t colOff = (size_t)PFD << 10;                // uniform, next col to issue
  unsigned lslot = (PFD << 10) & (RBYTES - 1);      // uniform LDS slot byte offset

  // prologue: issue cols 0..31
  #pragma unroll
  for (int c = 0; c < PFD; ++c) {
    __builtin_amdgcn_global_load_lds(
        (const __attribute__((address_space(1))) void*)(gW + ((size_t)c << 10) + laneOff),
        (__attribute__((address_space(3))) void*)(ring + ((unsigned)(c << 10))), 16, 0, 0);
  }
  asm volatile("s_waitcnt vmcnt(24)" ::: "memory");   // cols 0..7 landed

  u32x4 d0, d1, d2, d3, d4, d5, d6, d7;
  unsigned va0, va1, va2, va3, va4, va5, va6, va7;
#define RS_INIT(K) do { \
    d##K = *reinterpret_cast<const u32x4*>( \
        ring + ((((unsigned)(K - lane) & 127u) << 10) | (unsigned)(lane << 4))); \
    va##K = ((((unsigned)(8 + K - lane) & 127u) << 10) | (unsigned)(lane << 4)); \
  } while (0)
  RS_INIT(0); RS_INIT(1); RS_INIT(2); RS_INIT(3);
  RS_INIT(4); RS_INIT(5); RS_INIT(6); RS_INIT(7);
#undef RS_INIT

#define DTW_STEP(KK, BUF, VIN, VOUT, SDG, SEEDK, GUARD, RENORM) do {          \
    const int t_ = tb + (KK);                                                 \
    float nbUp_ = dppshr(VIN[7]);            /* neighbor end of t-1 */        \
    float nbDg_ = dppshr(VOUT[7]);           /* neighbor end of t-2 */        \
    float up_ = nbUp_ * sUp;                                                  \
    float dg_ = nbDg_ * (SDG);                                                \
    if (SEEDK) dg_ = dgSeed;                                                  \
    union { u32x4 u; __half h[8]; } cv_; cv_.u = d##BUF;                      \
    d##BUF = *reinterpret_cast<const u32x4*>(ring + va##BUF);  /* col t_+8 */ \
    va##BUF = (va##BUF + 8192u) & (RBYTES - 1);                               \
    __builtin_amdgcn_global_load_lds(                          /* col issue */\
        (const __attribute__((address_space(1))) void*)(gW + colOff + laneOff),\
        (__attribute__((address_space(3))) void*)(ring + lslot), 16, 0, 0);   \
    lslot = (lslot + 1024u) & (RBYTES - 1);                                   \
    colOff += ((t_ + PFD) < (T1 - 1)) ? 1024 : 0;  /* uniform; freezes @511 */\
    float wv_[8];                                                             \
    _Pragma("unroll")                                                         \
    for (int r = 0; r < 8; ++r) wv_[r] = __half2float(cv_.h[r]);              \
    bool act_ = true;                                                         \
    if (GUARD) { int j_ = t_ - lane; act_ = ((unsigned)j_ < (unsigned)T1); }  \
    if (act_) {                                                               \
      float c_ = fmaf(wv_[0], up_, wv_[0] * (dg_ + VIN[0]));                  \
      VOUT[0] = c_;                                                           \
      _Pragma("unroll")                                                       \
      for (int r = 1; r < 8; ++r) {                                           \
        c_ = fmaf(wv_[r], c_, wv_[r] * (VIN[r-1] + VIN[r]));                  \
        VOUT[r] = c_;                                                         \
      }                                                                       \
      if (RENORM) {                          /* exact pow2 renorm, per 16 */  \
        float m_ = fmaxf(fmaxf(fmaxf(VOUT[0],VOUT[1]),fmaxf(VOUT[2],VOUT[3])),\
                         fmaxf(fmaxf(VOUT[4],VOUT[5]),fmaxf(VOUT[6],VOUT[7])));\
        int e_ = (int)((__float_as_uint(m_) >> 23) & 0xFF) - 127;             \
        e_ = e_ < -126 ? -126 : (e_ > 126 ? 126 : e_);                        \
        float sc_ = __uint_as_float((unsigned)(127 - e_) << 23);              \
        _Pragma("unroll")                                                     \
        for (int r = 0; r < 8; ++r) VOUT[r] *= sc_;                           \
        B2p = B2; B2 -= (float)e_;                                            \
      }                                                                       \
    }                                                                         \
  } while (0)

#define DTW_GROUP(GUARD, SEED) do {                                           \
    asm volatile("s_waitcnt vmcnt(16)" ::: "memory");  /* cols <= tb+15 */    \
    float nbBn_ = dppshr(B2);                /* neighbor base, post-renorm */ \
    float nbBo_ = dppshr(B2p);               /* neighbor base, pre-renorm  */ \
    float sUp  = SCALEBITS(B2 - nbBn_);                                       \
    float sDg0 = SCALEBITS(B2 - nbBo_);                                       \
    DTW_STEP(0,  0, Va, Vb, sDg0, SEED,  GUARD, false);                       \
    DTW_STEP(1,  1, Vb, Va, sUp,  false, GUARD, false);                       \
    DTW_STEP(2,  2, Va, Vb, sUp,  false, GUARD, false);                       \
    DTW_STEP(3,  3, Vb, Va, sUp,  false, GUARD, false);                       \
    DTW_STEP(4,  4, Va, Vb, sUp,  false, GUARD, false);                       \
    DTW_STEP(5,  5, Vb, Va, sUp,  false, GUARD, false);                       \
    DTW_STEP(6,  6, Va, Vb, sUp,  false, GUARD, false);                       \
    DTW_STEP(7,  7, Vb, Va, sUp,  false, GUARD, false);                       \
    asm volatile("s_waitcnt vmcnt(16)" ::: "memory");  /* cols <= tb+23 */    \
    DTW_STEP(8,  0, Va, Vb, sUp,  false, GUARD, false);                       \
    DTW_STEP(9,  1, Vb, Va, sUp,  false, GUARD, false);                       \
    DTW_STEP(10, 2, Va, Vb, sUp,  false, GUARD, false);                       \
    DTW_STEP(11, 3, Vb, Va, sUp,  false, GUARD, false);                       \
    DTW_STEP(12, 4, Va, Vb, sUp,  false, GUARD, false);                       \
    DTW_STEP(13, 5, Vb, Va, sUp,  false, GUARD, false);                       \
    DTW_STEP(14, 6, Va, Vb, sUp,  false, GUARD, false);                       \
    DTW_STEP(15, 7, Vb, Va, sUp,  false, GUARD, true);                        \
  } while (0)

  // 36 groups of 16 steps = 576. Guarded: tb=0(seed),16,32,48 (head, t<64) and
  // tb=560 (protects lane63's final value at t=575). Middle 31 groups unguarded.
  { const int tb = 0; DTW_GROUP(true, true); }
  #pragma unroll 1
  for (int tb = 16; tb < 64; tb += 16)   DTW_GROUP(true,  false);
  #pragma unroll 1
  for (int tb = 64; tb < 560; tb += 16)  DTW_GROUP(false, false);
  { const int tb = 560; DTW_GROUP(true, false); }

  if (lane == 63) {
    // lane63's last ACTIVE step t=574 (KK14, even -> wrote Vb): col 511 = R[512][512].
    res[prob] = (B2 - log2f(Vb[7])) * 0.69314718055994530942f;
  }
#undef DTW_STEP
#undef DTW_GROUP
#undef SCALEBITS
}

// ---------------- kernel 4: combine ----------------
__global__ void k_combine(const float* __restrict__ res, float* __restrict__ out) {
  int b = threadIdx.x;
  if (b < NB) out[b] = res[b] - 0.5f * (res[NB + b] + res[2 * NB + b]);
}

extern "C" void kernel_launch(void* const* d_in, const int* in_sizes, int n_in,
                              void* d_out, int out_size, void* d_ws, size_t ws_size,
                              hipStream_t stream) {
  const float* x = (const float*)d_in[0];
  const float* y = (const float*)d_in[1];
  float* out = (float*)d_out;

  const size_t xb_off  = 0;
  const size_t yb_off  = (size_t)NB * T1 * DHEAD * sizeof(ushort);           // 2 MB
  const size_t W_off   = 2 * yb_off;                                          // 4 MB
  const size_t res_off = W_off + (size_t)3 * NB * T1 * T1 * sizeof(__half);   // +50.33 MB
  const size_t need    = res_off + NP * sizeof(float);

  if (ws_size < need) {
    hipMemsetAsync(d_out, 0xFF, (size_t)out_size * sizeof(float), stream);
    return;
  }

  ushort* xb  = (ushort*)((char*)d_ws + xb_off);
  ushort* yb  = (ushort*)((char*)d_ws + yb_off);
  __half* W   = (__half*)((char*)d_ws + W_off);
  float*  res = (float*)((char*)d_ws + res_off);

  hipLaunchKernelGGL(k_normalize, dim3(8192), dim3(256), 0, stream, x, y, xb, yb);
  hipLaunchKernelGGL(k_gemm_w, dim3(4, 4, 96), dim3(256), 0, stream, xb, yb, W);
  hipLaunchKernelGGL(k_dtw, dim3(NP), dim3(64), 0, stream, W, res);
  hipLaunchKernelGGL(k_combine, dim3(1), dim3(64), 0, stream, res, out);
}